// Round 9
// baseline (2264.429 us; speedup 1.0000x reference)
//
#include <hip/hip_runtime.h>

#define B_ 64
#define T_ 1024
#define I_ 16
#define H_ 512
#define O_ 3
#define NIN_ 103
#define NEX_ 409

// two-level i8 h encoding: h ~= S1*a + S2*b, exact i32 dots, fp32 combine
#define S1q (16.0f / 127.0f)
#define IS1q (127.0f / 16.0f)
#define S2q (S1q / 240.0f)
#define IS2q (240.0f * 127.0f / 16.0f)

#define XI_BYTES ((size_t)B_ * T_ * H_ * 4)  // 134217728

__device__ __forceinline__ int sdot4(unsigned a, unsigned b, int c) {
  return __builtin_amdgcn_sdot4((int)a, (int)b, c, false);
}
__device__ __forceinline__ float f16lo(unsigned u) {
  return (float)__builtin_bit_cast(_Float16, (unsigned short)(u & 0xffffu));
}
__device__ __forceinline__ float f16hi(unsigned u) {
  return (float)__builtin_bit_cast(_Float16, (unsigned short)(u >> 16));
}

// ---------------------------------------------------------------------------
// xi precompute: xi[bt][r] = x[bt] . W_i2h[r] + b_i2h[r] + b_h2h[r]
// ---------------------------------------------------------------------------
__global__ __launch_bounds__(256) void xi_pre_kernel(
    const float* __restrict__ x, const float* __restrict__ W_i2h,
    const float* __restrict__ b_i2h, const float* __restrict__ b_h2h,
    float* __restrict__ xi) {
  const size_t total = (size_t)B_ * T_ * H_;
  size_t idx = (size_t)blockIdx.x * 256 + threadIdx.x;
  const size_t stride = (size_t)gridDim.x * 256;
  for (; idx < total; idx += stride) {
    const size_t bt = idx >> 9;
    const int r = (int)(idx & (H_ - 1));
    const float* xr = x + bt * I_;
    const float* wr = W_i2h + (size_t)r * I_;
    float s = b_i2h[r] + b_h2h[r];
#pragma unroll
    for (int i = 0; i < I_; ++i) s += wr[i] * xr[i];
    xi[idx] = s;
  }
}

// ---------------------------------------------------------------------------
// Single-CU-per-batch RNN, 512 threads (8 waves). Thread (rg=tid>>4,
// kc=tid&15) owns rows [16rg,16rg+16) x k-cols [32kc,32kc+32) of W_h2h as
// row-scaled i8 in 128 VGPRs (launch_bounds(512,2) -> 256-VGPR budget, no
// AGPR banking -- the R8 bug). Recurrence via sdot4 on two-level i8 h from
// double-buffered LDS; 4-level width-16 reduce-scatter leaves row `tid` on
// thread `tid` (coalesced epilogue). 1 barrier/step, zero cross-block
// traffic, deterministic.
// ---------------------------------------------------------------------------
template <bool PRE>
__global__ __launch_bounds__(512, 2) void rnn_1cu(
    const float* __restrict__ x, const float* __restrict__ noise,
    const float* __restrict__ W_i2h, const float* __restrict__ b_i2h,
    const float* __restrict__ W_h2h, const float* __restrict__ b_h2h,
    const int* __restrict__ taup, const int* __restrict__ dtp,
    const float* __restrict__ xi_pre, float* __restrict__ out_rnn) {
  __shared__ char ha_s[2][16 * 48];  // level-1 bytes; chunk stride 48
  __shared__ char hb_s[2][16 * 48];  // level-2 bytes
  __shared__ float x_s[2][I_];
  __shared__ unsigned wi_s[H_ * 12];  // (!PRE only; DCE'd for PRE)

  const int tid = threadIdx.x;
  const int b = blockIdx.x;
  const int rg = tid >> 4;  // 0..31: row group of 16
  const int kc = tid & 15;  // 0..15: k-chunk of 32

  const float alpha = (float)dtp[0] / (float)taup[0];
  const float nzscale = (float)(sqrt(2.0 * (double)alpha) * 0.01);

  // ---- setup: two-pass W quantization into 128 VGPRs ----
  const float* wbase = W_h2h + (size_t)(16 * rg) * H_ + 32 * kc;
  float m[16];
#pragma unroll
  for (int ro = 0; ro < 16; ++ro) {
    float mx = 0.f;
#pragma unroll
    for (int j = 0; j < 8; ++j) {
      const float4 f = *(const float4*)(wbase + (size_t)ro * H_ + 4 * j);
      mx = fmaxf(mx, fmaxf(fmaxf(fabsf(f.x), fabsf(f.y)),
                           fmaxf(fabsf(f.z), fabsf(f.w))));
    }
    m[ro] = mx;
  }
#pragma unroll
  for (int hop = 1; hop <= 8; hop <<= 1)
#pragma unroll
    for (int ro = 0; ro < 16; ++ro)
      m[ro] = fmaxf(m[ro], __shfl_xor(m[ro], hop, 16));
  unsigned wreg[128];
#pragma unroll
  for (int ro = 0; ro < 16; ++ro) {
    const float inv = (m[ro] > 0.f) ? 127.0f / m[ro] : 0.f;
#pragma unroll
    for (int j = 0; j < 8; ++j) {
      const float4 f = *(const float4*)(wbase + (size_t)ro * H_ + 4 * j);
      const int q0 = (int)rintf(f.x * inv), q1 = (int)rintf(f.y * inv);
      const int q2 = (int)rintf(f.z * inv), q3 = (int)rintf(f.w * inv);
      wreg[ro * 8 + j] = (unsigned)(q0 & 255) | ((unsigned)(q1 & 255) << 8) |
                         ((unsigned)(q2 & 255) << 16) |
                         ((unsigned)(q3 & 255) << 24);
    }
  }
  // s_own for row 16rg+kc: 4-level static select tree over m[0..15]
  float s_own;
  {
    const float t01 = (kc & 1) ? m[1] : m[0];
    const float t23 = (kc & 1) ? m[3] : m[2];
    const float t45 = (kc & 1) ? m[5] : m[4];
    const float t67 = (kc & 1) ? m[7] : m[6];
    const float t89 = (kc & 1) ? m[9] : m[8];
    const float tAB = (kc & 1) ? m[11] : m[10];
    const float tCD = (kc & 1) ? m[13] : m[12];
    const float tEF = (kc & 1) ? m[15] : m[14];
    const float u0 = (kc & 2) ? t23 : t01;
    const float u1 = (kc & 2) ? t67 : t45;
    const float u2 = (kc & 2) ? tAB : t89;
    const float u3 = (kc & 2) ? tEF : tCD;
    const float p0 = (kc & 4) ? u1 : u0;
    const float p1 = (kc & 4) ? u3 : u2;
    s_own = ((kc & 8) ? p1 : p0) * (1.0f / 127.0f);
  }

  if (!PRE) {  // W_i2h row as f16 pairs + fused bias (thread tid = row tid)
    const float* wr = W_i2h + (size_t)tid * I_;
#pragma unroll
    for (int i2 = 0; i2 < 8; ++i2) {
      const unsigned short lo =
          __builtin_bit_cast(unsigned short, (_Float16)wr[2 * i2]);
      const unsigned short hi =
          __builtin_bit_cast(unsigned short, (_Float16)wr[2 * i2 + 1]);
      wi_s[tid * 12 + i2] = (unsigned)lo | ((unsigned)hi << 16);
    }
    wi_s[tid * 12 + 8] = __float_as_uint(b_i2h[tid] + b_h2h[tid]);
  }
  {
    // zero both parities of both h buffers (768 B each array)
    for (int i = tid; i < 16 * 48; i += 512) {
      ha_s[0][i] = 0; ha_s[1][i] = 0;
      hb_s[0][i] = 0; hb_s[1][i] = 0;
    }
  }
  if (tid < I_) x_s[0][tid] = x[(size_t)b * T_ * I_ + tid];
  out_rnn[(size_t)b * (T_ + 1) * H_ + tid] = 0.f;
  __syncthreads();

  const size_t nbase = (size_t)b * T_ * H_;
  const size_t obase = (size_t)b * (T_ + 1) * H_;
  const int wchunk = tid >> 5;   // h-byte chunk for my own row
  const int widx = tid & 31;

  for (int t = 0; t < T_; ++t) {
    const int p = t & 1;
    // per-step globals issued first (consumed at epilogue; hide under dots)
    const float nz = noise[nbase + (size_t)t * H_ + tid];
    float xiv = 0.f;
    if (PRE) xiv = xi_pre[nbase + (size_t)t * H_ + tid];
    if (tid < I_) {
      const int tn = (t < T_ - 1) ? t + 1 : t;
      x_s[p ^ 1][tid] = x[((size_t)b * T_ + tn) * I_ + tid];
    }
    // h(t) two-level bytes for my k-chunk
    const char* hap = &ha_s[p][kc * 48];
    const char* hbp = &hb_s[p][kc * 48];
    const uint4 A0 = *(const uint4*)hap;
    const uint4 A1 = *(const uint4*)(hap + 16);
    const uint4 B0 = *(const uint4*)hbp;
    const uint4 B1 = *(const uint4*)(hbp + 16);
    float v[16];
#pragma unroll
    for (int ro = 0; ro < 16; ++ro) {
      int a = 0, bb = 0;
      a = sdot4(wreg[ro * 8 + 0], A0.x, a);
      a = sdot4(wreg[ro * 8 + 1], A0.y, a);
      a = sdot4(wreg[ro * 8 + 2], A0.z, a);
      a = sdot4(wreg[ro * 8 + 3], A0.w, a);
      a = sdot4(wreg[ro * 8 + 4], A1.x, a);
      a = sdot4(wreg[ro * 8 + 5], A1.y, a);
      a = sdot4(wreg[ro * 8 + 6], A1.z, a);
      a = sdot4(wreg[ro * 8 + 7], A1.w, a);
      bb = sdot4(wreg[ro * 8 + 0], B0.x, bb);
      bb = sdot4(wreg[ro * 8 + 1], B0.y, bb);
      bb = sdot4(wreg[ro * 8 + 2], B0.z, bb);
      bb = sdot4(wreg[ro * 8 + 3], B0.w, bb);
      bb = sdot4(wreg[ro * 8 + 4], B1.x, bb);
      bb = sdot4(wreg[ro * 8 + 5], B1.y, bb);
      bb = sdot4(wreg[ro * 8 + 6], B1.z, bb);
      bb = sdot4(wreg[ro * 8 + 7], B1.w, bb);
      v[ro] = (float)a * S1q + (float)bb * S2q;
    }
    // 4-level reduce-scatter across 16 kc lanes; row bit_i <- kc bit_i
#pragma unroll
    for (int j = 0; j < 8; ++j) {
      const float tl = __shfl_xor(v[j], 8, 16);
      const float th = __shfl_xor(v[j + 8], 8, 16);
      v[j] = (kc & 8) ? (v[j + 8] + th) : (v[j] + tl);
    }
#pragma unroll
    for (int j = 0; j < 4; ++j) {
      const float tl = __shfl_xor(v[j], 4, 16);
      const float th = __shfl_xor(v[j + 4], 4, 16);
      v[j] = (kc & 4) ? (v[j + 4] + th) : (v[j] + tl);
    }
#pragma unroll
    for (int j = 0; j < 2; ++j) {
      const float tl = __shfl_xor(v[j], 2, 16);
      const float th = __shfl_xor(v[j + 2], 2, 16);
      v[j] = (kc & 2) ? (v[j + 2] + th) : (v[j] + tl);
    }
    float rec;
    {
      const float tl = __shfl_xor(v[0], 1, 16);
      const float th = __shfl_xor(v[1], 1, 16);
      rec = (kc & 1) ? (v[1] + th) : (v[0] + tl);
    }
    // epilogue: every thread finishes its own row (r_own = tid)
    float xfull;
    if (PRE) {
      xfull = xiv;
    } else {
      const uint4 w0 = *(const uint4*)&wi_s[tid * 12];
      const uint4 w1 = *(const uint4*)&wi_s[tid * 12 + 4];
      float s = __uint_as_float(wi_s[tid * 12 + 8]);
      s += f16lo(w0.x) * x_s[p][0] + f16hi(w0.x) * x_s[p][1];
      s += f16lo(w0.y) * x_s[p][2] + f16hi(w0.y) * x_s[p][3];
      s += f16lo(w0.z) * x_s[p][4] + f16hi(w0.z) * x_s[p][5];
      s += f16lo(w0.w) * x_s[p][6] + f16hi(w0.w) * x_s[p][7];
      s += f16lo(w1.x) * x_s[p][8] + f16hi(w1.x) * x_s[p][9];
      s += f16lo(w1.y) * x_s[p][10] + f16hi(w1.y) * x_s[p][11];
      s += f16lo(w1.z) * x_s[p][12] + f16hi(w1.z) * x_s[p][13];
      s += f16lo(w1.w) * x_s[p][14] + f16hi(w1.w) * x_s[p][15];
      xfull = s;
    }
    const float pre = alpha * (xfull + rec * s_own) + nzscale * nz;
    const float h = fmaxf(pre, 0.f);
    out_rnn[obase + (size_t)(t + 1) * H_ + tid] = h;
    int aq = (int)rintf(h * IS1q);
    aq = min(aq, 127);
    const float res = h - (float)aq * S1q;
    const int bq = (int)rintf(res * IS2q);
    ha_s[p ^ 1][wchunk * 48 + widx] = (char)aq;
    hb_s[p ^ 1][wchunk * 48 + widx] = (char)bq;
    __syncthreads();  // h(t+1) + x(t+1) staged; buffers flip
  }
}

// ---------------------------------------------------------------------------
// Post-pass: out_net[b][t] = W_h2o . h_ex(b,t) + b_h2o (t>=1), zeros at t=0.
// ---------------------------------------------------------------------------
__global__ __launch_bounds__(256) void h2o_kernel(
    const float* __restrict__ out_rnn, const float* __restrict__ W_h2o,
    const float* __restrict__ b_h2o, float* __restrict__ out_net) {
  __shared__ float w3[3 * 416];
  const int tid = threadIdx.x;
  for (int idx = tid; idx < O_ * NEX_; idx += 256) {
    const int o = idx / NEX_, e = idx - o * NEX_;
    w3[o * 416 + e] = W_h2o[idx];
  }
  __syncthreads();
  const int wv = tid >> 6, ln = tid & 63;
  const int task = blockIdx.x * 4 + wv;
  if (task >= B_ * (T_ + 1)) return;
  const int bb = task / (T_ + 1), t = task - bb * (T_ + 1);
  float* dst = out_net + (size_t)task * O_;
  if (t == 0) {
    if (ln < O_) dst[ln] = 0.f;
    return;
  }
  const float* hrow = out_rnn + (size_t)task * H_ + NIN_;
  float a0 = 0.f, a1 = 0.f, a2 = 0.f;
  for (int k = ln; k < NEX_; k += 64) {
    const float hv = hrow[k];
    a0 += hv * w3[k];
    a1 += hv * w3[416 + k];
    a2 += hv * w3[832 + k];
  }
#pragma unroll
  for (int off = 32; off >= 1; off >>= 1) {
    a0 += __shfl_xor(a0, off, 64);
    a1 += __shfl_xor(a1, off, 64);
    a2 += __shfl_xor(a2, off, 64);
  }
  if (ln == 0) {
    dst[0] = a0 + b_h2o[0];
    dst[1] = a1 + b_h2o[1];
    dst[2] = a2 + b_h2o[2];
  }
}

extern "C" void kernel_launch(void* const* d_in, const int* in_sizes, int n_in,
                              void* d_out, int out_size, void* d_ws,
                              size_t ws_size, hipStream_t stream) {
  const float* x = (const float*)d_in[0];
  const float* noise = (const float*)d_in[1];
  const float* W_i2h = (const float*)d_in[2];
  const float* b_i2h = (const float*)d_in[3];
  const float* W_h2h = (const float*)d_in[4];
  const float* b_h2h = (const float*)d_in[5];
  const float* W_h2o = (const float*)d_in[6];
  const float* b_h2o = (const float*)d_in[7];
  const int* tau = (const int*)d_in[8];
  const int* dt = (const int*)d_in[9];

  float* out_net = (float*)d_out;
  float* out_rnn = (float*)d_out + (size_t)B_ * (T_ + 1) * O_;

  if (d_ws != nullptr && ws_size >= XI_BYTES) {
    float* xi = (float*)d_ws;
    hipLaunchKernelGGL(xi_pre_kernel, dim3(2048), dim3(256), 0, stream, x,
                       W_i2h, b_i2h, b_h2h, xi);
    hipLaunchKernelGGL((rnn_1cu<true>), dim3(B_), dim3(512), 0, stream, x,
                       noise, W_i2h, b_i2h, W_h2h, b_h2h, tau, dt, xi, out_rnn);
  } else {
    hipLaunchKernelGGL((rnn_1cu<false>), dim3(B_), dim3(512), 0, stream, x,
                       noise, W_i2h, b_i2h, W_h2h, b_h2h, tau, dt,
                       (const float*)nullptr, out_rnn);
  }
  hipLaunchKernelGGL(h2o_kernel, dim3((B_ * (T_ + 1) + 3) / 4), dim3(256), 0,
                     stream, out_rnn, W_h2o, b_h2o, out_net);
}

// Round 11
// 2004.272 us; speedup vs baseline: 1.1298x; 1.1298x over previous
//
#include <hip/hip_runtime.h>

#define B_ 64
#define T_ 1024
#define I_ 16
#define H_ 512
#define O_ 3
#define NIN_ 103
#define NEX_ 409

// two-level i8 h encoding: h ~= S1*a + S2*b, exact i32 dots, fp32 combine
#define S1q (16.0f / 127.0f)
#define IS1q (127.0f / 16.0f)
#define S2q (S1q / 240.0f)
#define IS2q (240.0f * 127.0f / 16.0f)

#define XI_BYTES ((size_t)B_ * T_ * H_ * 4)  // 134217728

__device__ __forceinline__ int sdot4(unsigned a, unsigned b, int c) {
  return __builtin_amdgcn_sdot4((int)a, (int)b, c, false);
}
__device__ __forceinline__ float f16lo(unsigned u) {
  return (float)__builtin_bit_cast(_Float16, (unsigned short)(u & 0xffffu));
}
__device__ __forceinline__ float f16hi(unsigned u) {
  return (float)__builtin_bit_cast(_Float16, (unsigned short)(u >> 16));
}
// VALU cross-lane via DPP (no ds_bpermute). CTRL must be an immediate ->
// template parameter (R10 compile fix). Direction-safe ctrls only:
// 0x140 row_mirror (l^15 within 16), 0x128 row_ror:8 (l^8 within 16),
// quad_perm 0x4E (l^2), 0xB1 (l^1).
template <int CTRL>
__device__ __forceinline__ float dppf(float v) {
  return __int_as_float(__builtin_amdgcn_update_dpp(
      0, __float_as_int(v), CTRL, 0xF, 0xF, true));
}
#define DPP_X1 0xB1   // quad_perm [1,0,3,2]
#define DPP_X2 0x4E   // quad_perm [2,3,0,1]
#define DPP_X8 0x128  // row_ror:8
#define DPP_X15 0x140 // row_mirror

// ---------------------------------------------------------------------------
// xi precompute: xi[bt][r] = x[bt] . W_i2h[r] + b_i2h[r] + b_h2h[r]
// ---------------------------------------------------------------------------
__global__ __launch_bounds__(256) void xi_pre_kernel(
    const float* __restrict__ x, const float* __restrict__ W_i2h,
    const float* __restrict__ b_i2h, const float* __restrict__ b_h2h,
    float* __restrict__ xi) {
  const size_t total = (size_t)B_ * T_ * H_;
  size_t idx = (size_t)blockIdx.x * 256 + threadIdx.x;
  const size_t stride = (size_t)gridDim.x * 256;
  for (; idx < total; idx += stride) {
    const size_t bt = idx >> 9;
    const int r = (int)(idx & (H_ - 1));
    const float* xr = x + bt * I_;
    const float* wr = W_i2h + (size_t)r * I_;
    float s = b_i2h[r] + b_h2h[r];
#pragma unroll
    for (int i = 0; i < I_; ++i) s += wr[i] * xr[i];
    xi[idx] = s;
  }
}

// ---------------------------------------------------------------------------
// Single-CU-per-batch RNN, 1024 threads (16 waves, 4/SIMD). Thread
// (rg=tid>>4, kc=tid&15) owns rows [8rg,8rg+8) x k-cols [32kc,32kc+32) of
// W_h2h as row-scaled i8 in 64 VGPRs (fits the 128-VGPR budget of
// launch_bounds(1024,4): no AGPR banking, no spill). Recurrence via sdot4 on
// two-level i8 h from double-buffered LDS. Reduce-scatter across the 16 kc
// lanes is ALL-VALU DPP (masks {15,8,2,1}: mirror, ror8, quad_perms --
// direction-unambiguous), eliminating the R9 ds_bpermute storm on the LDS
// pipe. One barrier/step, zero cross-block traffic, deterministic.
// Scatter row map: r_own = 8rg + 4*kc[2] + 2*kc[3] + kc[1]; lane pairs
// (kc, kc^1) duplicate the final sum; even lane stores.
// ---------------------------------------------------------------------------
template <bool PRE>
__global__ __launch_bounds__(1024, 4) void rnn_1cu(
    const float* __restrict__ x, const float* __restrict__ noise,
    const float* __restrict__ W_i2h, const float* __restrict__ b_i2h,
    const float* __restrict__ W_h2h, const float* __restrict__ b_h2h,
    const int* __restrict__ taup, const int* __restrict__ dtp,
    const float* __restrict__ xi_pre, float* __restrict__ out_rnn) {
  __align__(16) __shared__ char ha_s[2][16 * 48];  // level-1 bytes
  __align__(16) __shared__ char hb_s[2][16 * 48];  // level-2 bytes
  __shared__ float x_s[2][I_];        // !PRE only
  __shared__ unsigned wi_s[H_ * 12];  // !PRE only (DCE'd for PRE)

  const int tid = threadIdx.x;
  const int b = blockIdx.x;
  const int rg = tid >> 4;  // 0..63: row group of 8
  const int kc = tid & 15;  // 0..15: k-chunk of 32

  const float alpha = (float)dtp[0] / (float)taup[0];
  const float nzscale = (float)(sqrt(2.0 * (double)alpha) * 0.01);

  // ---- setup: two-pass W quantization into 64 VGPRs ----
  const float* wbase = W_h2h + (size_t)(8 * rg) * H_ + 32 * kc;
  float m[8];
#pragma unroll
  for (int ro = 0; ro < 8; ++ro) {
    float mx = 0.f;
#pragma unroll
    for (int j = 0; j < 8; ++j) {
      const float4 f = *(const float4*)(wbase + (size_t)ro * H_ + 4 * j);
      mx = fmaxf(mx, fmaxf(fmaxf(fabsf(f.x), fabsf(f.y)),
                           fmaxf(fabsf(f.z), fabsf(f.w))));
    }
    m[ro] = mx;
  }
#pragma unroll
  for (int hop = 1; hop <= 8; hop <<= 1)
#pragma unroll
    for (int ro = 0; ro < 8; ++ro)
      m[ro] = fmaxf(m[ro], __shfl_xor(m[ro], hop, 16));  // setup-only bperm
  unsigned wreg[64];
#pragma unroll
  for (int ro = 0; ro < 8; ++ro) {
    const float inv = (m[ro] > 0.f) ? 127.0f / m[ro] : 0.f;
#pragma unroll
    for (int j = 0; j < 8; ++j) {
      const float4 f = *(const float4*)(wbase + (size_t)ro * H_ + 4 * j);
      const int q0 = (int)rintf(f.x * inv), q1 = (int)rintf(f.y * inv);
      const int q2 = (int)rintf(f.z * inv), q3 = (int)rintf(f.w * inv);
      wreg[ro * 8 + j] = (unsigned)(q0 & 255) | ((unsigned)(q1 & 255) << 8) |
                         ((unsigned)(q2 & 255) << 16) |
                         ((unsigned)(q3 & 255) << 24);
    }
  }
  // s_own for r_own's local index rloc = 4a+2b+c (a=kc[2], b=kc[3], c=kc[1])
  float s_own;
  {
    const bool a = (kc >> 2) & 1, bb = (kc >> 3) & 1, c = (kc >> 1) & 1;
    const float mA = c ? m[1] : m[0];
    const float mB = c ? m[3] : m[2];
    const float mC = c ? m[5] : m[4];
    const float mD = c ? m[7] : m[6];
    const float mE = bb ? mB : mA;
    const float mF = bb ? mD : mC;
    s_own = (a ? mF : mE) * (1.0f / 127.0f);
  }
  const int r_own = 8 * rg + 4 * ((kc >> 2) & 1) + 2 * ((kc >> 3) & 1) +
                    ((kc >> 1) & 1);

  if (!PRE && tid < H_) {  // W_i2h row as f16 pairs + fused bias
    const float* wr = W_i2h + (size_t)tid * I_;
#pragma unroll
    for (int i2 = 0; i2 < 8; ++i2) {
      const unsigned short lo =
          __builtin_bit_cast(unsigned short, (_Float16)wr[2 * i2]);
      const unsigned short hi =
          __builtin_bit_cast(unsigned short, (_Float16)wr[2 * i2 + 1]);
      wi_s[tid * 12 + i2] = (unsigned)lo | ((unsigned)hi << 16);
    }
    wi_s[tid * 12 + 8] = __float_as_uint(b_i2h[tid] + b_h2h[tid]);
  }
  if (tid < 16 * 48) {  // zero both parities of both h buffers
    ha_s[0][tid] = 0; ha_s[1][tid] = 0;
    hb_s[0][tid] = 0; hb_s[1][tid] = 0;
  }
  if (!PRE && tid < I_) x_s[0][tid] = x[(size_t)b * T_ * I_ + tid];
  if (tid < H_) out_rnn[(size_t)b * (T_ + 1) * H_ + tid] = 0.f;
  __syncthreads();

  const size_t nbase = (size_t)b * T_ * H_;
  const size_t obase = (size_t)b * (T_ + 1) * H_;
  const size_t xbase = (size_t)b * T_ * I_;
  const int wchunk = r_own >> 5, widx = r_own & 31;

  // prefetch step-0 per-row globals
  float nzv = noise[nbase + r_own];
  float xiv = PRE ? xi_pre[nbase + r_own] : 0.f;

  for (int t = 0; t < T_; ++t) {
    const int p = t & 1;
    // issue NEXT step's loads first (consumed after the barrier; their
    // waits never drain this step's stores)
    const int tn = (t < T_ - 1) ? t + 1 : t;
    const float nz_n = noise[nbase + (size_t)tn * H_ + r_own];
    float xi_n = 0.f;
    if (PRE) xi_n = xi_pre[nbase + (size_t)tn * H_ + r_own];
    if (!PRE && tid < I_) x_s[p ^ 1][tid] = x[xbase + (size_t)tn * I_ + tid];

    // h(t) two-level bytes for my k-chunk (2-way-conflict-free, 4-way bcast)
    const char* hap = &ha_s[p][kc * 48];
    const char* hbp = &hb_s[p][kc * 48];
    const uint4 A0 = *(const uint4*)hap;
    const uint4 A1 = *(const uint4*)(hap + 16);
    const uint4 B0 = *(const uint4*)hbp;
    const uint4 B1 = *(const uint4*)(hbp + 16);
    float v[8];
#pragma unroll
    for (int ro = 0; ro < 8; ++ro) {
      int a = 0, bb = 0;
      a = sdot4(wreg[ro * 8 + 0], A0.x, a);
      a = sdot4(wreg[ro * 8 + 1], A0.y, a);
      a = sdot4(wreg[ro * 8 + 2], A0.z, a);
      a = sdot4(wreg[ro * 8 + 3], A0.w, a);
      a = sdot4(wreg[ro * 8 + 4], A1.x, a);
      a = sdot4(wreg[ro * 8 + 5], A1.y, a);
      a = sdot4(wreg[ro * 8 + 6], A1.z, a);
      a = sdot4(wreg[ro * 8 + 7], A1.w, a);
      bb = sdot4(wreg[ro * 8 + 0], B0.x, bb);
      bb = sdot4(wreg[ro * 8 + 1], B0.y, bb);
      bb = sdot4(wreg[ro * 8 + 2], B0.z, bb);
      bb = sdot4(wreg[ro * 8 + 3], B0.w, bb);
      bb = sdot4(wreg[ro * 8 + 4], B1.x, bb);
      bb = sdot4(wreg[ro * 8 + 5], B1.y, bb);
      bb = sdot4(wreg[ro * 8 + 6], B1.z, bb);
      bb = sdot4(wreg[ro * 8 + 7], B1.w, bb);
      v[ro] = fmaf((float)bb, S2q, (float)a * S1q);
    }
    // ALL-VALU reduce-scatter over 16 kc lanes: masks {15, 8, 2} select,
    // mask {1} final butterfly. (rank-4 span => full 16-lane sum.)
#pragma unroll
    for (int j = 0; j < 4; ++j) {  // L15: partner l^15 (row_mirror)
      const float tl = dppf<DPP_X15>(v[j]);
      const float th = dppf<DPP_X15>(v[j + 4]);
      v[j] = (kc & 4) ? (v[j + 4] + th) : (v[j] + tl);
    }
#pragma unroll
    for (int j = 0; j < 2; ++j) {  // L8: partner l^8 (row_ror:8)
      const float tl = dppf<DPP_X8>(v[j]);
      const float th = dppf<DPP_X8>(v[j + 2]);
      v[j] = (kc & 8) ? (v[j + 2] + th) : (v[j] + tl);
    }
    {  // L2: partner l^2 (quad_perm)
      const float tl = dppf<DPP_X2>(v[0]);
      const float th = dppf<DPP_X2>(v[1]);
      v[0] = (kc & 2) ? (v[1] + th) : (v[0] + tl);
    }
    const float rec = v[0] + dppf<DPP_X1>(v[0]);  // L1 butterfly

    // epilogue: both lanes of the (kc, kc^1) pair compute; even lane stores
    float xfull;
    if (PRE) {
      xfull = xiv;
    } else {
      const uint4 w0 = *(const uint4*)&wi_s[r_own * 12];
      const uint4 w1 = *(const uint4*)&wi_s[r_own * 12 + 4];
      float s = __uint_as_float(wi_s[r_own * 12 + 8]);
      s += f16lo(w0.x) * x_s[p][0] + f16hi(w0.x) * x_s[p][1];
      s += f16lo(w0.y) * x_s[p][2] + f16hi(w0.y) * x_s[p][3];
      s += f16lo(w0.z) * x_s[p][4] + f16hi(w0.z) * x_s[p][5];
      s += f16lo(w0.w) * x_s[p][6] + f16hi(w0.w) * x_s[p][7];
      s += f16lo(w1.x) * x_s[p][8] + f16hi(w1.x) * x_s[p][9];
      s += f16lo(w1.y) * x_s[p][10] + f16hi(w1.y) * x_s[p][11];
      s += f16lo(w1.z) * x_s[p][12] + f16hi(w1.z) * x_s[p][13];
      s += f16lo(w1.w) * x_s[p][14] + f16hi(w1.w) * x_s[p][15];
      xfull = s;
    }
    const float pre = alpha * (xfull + rec * s_own) + nzscale * nzv;
    const float h = fmaxf(pre, 0.f);
    if ((kc & 1) == 0) {
      out_rnn[obase + (size_t)(t + 1) * H_ + r_own] = h;
      int aq = (int)rintf(h * IS1q);
      aq = min(aq, 127);
      const float res = h - (float)aq * S1q;
      const int bq = (int)rintf(res * IS2q);
      ha_s[p ^ 1][wchunk * 48 + widx] = (char)aq;
      hb_s[p ^ 1][wchunk * 48 + widx] = (char)bq;
    }
    __syncthreads();  // h(t+1) staged; buffers flip
    nzv = nz_n;
    xiv = xi_n;
  }
}

// ---------------------------------------------------------------------------
// Post-pass: out_net[b][t] = W_h2o . h_ex(b,t) + b_h2o (t>=1), zeros at t=0.
// ---------------------------------------------------------------------------
__global__ __launch_bounds__(256) void h2o_kernel(
    const float* __restrict__ out_rnn, const float* __restrict__ W_h2o,
    const float* __restrict__ b_h2o, float* __restrict__ out_net) {
  __shared__ float w3[3 * 416];
  const int tid = threadIdx.x;
  for (int idx = tid; idx < O_ * NEX_; idx += 256) {
    const int o = idx / NEX_, e = idx - o * NEX_;
    w3[o * 416 + e] = W_h2o[idx];
  }
  __syncthreads();
  const int wv = tid >> 6, ln = tid & 63;
  const int task = blockIdx.x * 4 + wv;
  if (task >= B_ * (T_ + 1)) return;
  const int bb = task / (T_ + 1), t = task - bb * (T_ + 1);
  float* dst = out_net + (size_t)task * O_;
  if (t == 0) {
    if (ln < O_) dst[ln] = 0.f;
    return;
  }
  const float* hrow = out_rnn + (size_t)task * H_ + NIN_;
  float a0 = 0.f, a1 = 0.f, a2 = 0.f;
  for (int k = ln; k < NEX_; k += 64) {
    const float hv = hrow[k];
    a0 += hv * w3[k];
    a1 += hv * w3[416 + k];
    a2 += hv * w3[832 + k];
  }
#pragma unroll
  for (int off = 32; off >= 1; off >>= 1) {
    a0 += __shfl_xor(a0, off, 64);
    a1 += __shfl_xor(a1, off, 64);
    a2 += __shfl_xor(a2, off, 64);
  }
  if (ln == 0) {
    dst[0] = a0 + b_h2o[0];
    dst[1] = a1 + b_h2o[1];
    dst[2] = a2 + b_h2o[2];
  }
}

extern "C" void kernel_launch(void* const* d_in, const int* in_sizes, int n_in,
                              void* d_out, int out_size, void* d_ws,
                              size_t ws_size, hipStream_t stream) {
  const float* x = (const float*)d_in[0];
  const float* noise = (const float*)d_in[1];
  const float* W_i2h = (const float*)d_in[2];
  const float* b_i2h = (const float*)d_in[3];
  const float* W_h2h = (const float*)d_in[4];
  const float* b_h2h = (const float*)d_in[5];
  const float* W_h2o = (const float*)d_in[6];
  const float* b_h2o = (const float*)d_in[7];
  const int* tau = (const int*)d_in[8];
  const int* dt = (const int*)d_in[9];

  float* out_net = (float*)d_out;
  float* out_rnn = (float*)d_out + (size_t)B_ * (T_ + 1) * O_;

  if (d_ws != nullptr && ws_size >= XI_BYTES) {
    float* xi = (float*)d_ws;
    hipLaunchKernelGGL(xi_pre_kernel, dim3(2048), dim3(256), 0, stream, x,
                       W_i2h, b_i2h, b_h2h, xi);
    hipLaunchKernelGGL((rnn_1cu<true>), dim3(B_), dim3(1024), 0, stream, x,
                       noise, W_i2h, b_i2h, W_h2h, b_h2h, tau, dt, xi, out_rnn);
  } else {
    hipLaunchKernelGGL((rnn_1cu<false>), dim3(B_), dim3(1024), 0, stream, x,
                       noise, W_i2h, b_i2h, W_h2h, b_h2h, tau, dt,
                       (const float*)nullptr, out_rnn);
  }
  hipLaunchKernelGGL(h2o_kernel, dim3((B_ * (T_ + 1) + 3) / 4), dim3(256), 0,
                     stream, out_rnn, W_h2o, b_h2o, out_net);
}

// Round 12
// 1891.743 us; speedup vs baseline: 1.1970x; 1.0595x over previous
//
#include <hip/hip_runtime.h>

#define B_ 64
#define T_ 1024
#define I_ 16
#define H_ 512
#define O_ 3
#define NIN_ 103
#define NEX_ 409

// two-level i8 h encoding: h ~= S1*a + S2*b, exact i32 dots, fp32 combine
#define S1q (16.0f / 127.0f)
#define IS1q (127.0f / 16.0f)
#define S2q (S1q / 240.0f)
#define IS2q (240.0f * 127.0f / 16.0f)

#define WQ_BYTES ((size_t)H_ * H_)        // 262144 i8
#define SC_BYTES ((size_t)H_ * 4)         // 2048
#define XI_OFF (WQ_BYTES + SC_BYTES)      // 264192 (16B aligned)
#define XI_BYTES ((size_t)B_ * T_ * H_ * 4)  // 134217728
#define NEED2 (XI_OFF + XI_BYTES)

__device__ __forceinline__ int sdot4(unsigned a, unsigned b, int c) {
  return __builtin_amdgcn_sdot4((int)a, (int)b, c, false);
}
__device__ __forceinline__ float f16lo(unsigned u) {
  return (float)__builtin_bit_cast(_Float16, (unsigned short)(u & 0xffffu));
}
__device__ __forceinline__ float f16hi(unsigned u) {
  return (float)__builtin_bit_cast(_Float16, (unsigned short)(u >> 16));
}
// VALU cross-lane via DPP; CTRL must be immediate (template param).
template <int CTRL>
__device__ __forceinline__ float dppf(float v) {
  return __int_as_float(__builtin_amdgcn_update_dpp(
      0, __float_as_int(v), CTRL, 0xF, 0xF, true));
}
#define DPP_X1 0xB1   // quad_perm [1,0,3,2]
#define DPP_X2 0x4E   // quad_perm [2,3,0,1]
#define DPP_X8 0x128  // row_ror:8
#define DPP_X15 0x140 // row_mirror

// ---------------------------------------------------------------------------
// W quantization pre-pass: one wave per row. wq[r*128+w] = 4 packed i8;
// sc[r] = rowmax/127. Removes the RNN kernel's setup register-pressure peak
// (the cause of wreg AGPR-banking in R8/R9/R11).
// ---------------------------------------------------------------------------
__global__ __launch_bounds__(64) void quant_w(const float* __restrict__ W,
                                              unsigned* __restrict__ wq,
                                              float* __restrict__ sc) {
  const int r = blockIdx.x, l = threadIdx.x;
  const float* row = W + (size_t)r * H_ + 8 * l;
  float4 f0 = *(const float4*)row;
  float4 f1 = *(const float4*)(row + 4);
  float mx = fmaxf(fmaxf(fmaxf(fabsf(f0.x), fabsf(f0.y)),
                         fmaxf(fabsf(f0.z), fabsf(f0.w))),
                   fmaxf(fmaxf(fabsf(f1.x), fabsf(f1.y)),
                         fmaxf(fabsf(f1.z), fabsf(f1.w))));
#pragma unroll
  for (int off = 32; off >= 1; off >>= 1) mx = fmaxf(mx, __shfl_xor(mx, off, 64));
  const float inv = (mx > 0.f) ? 127.0f / mx : 0.f;
  const int q0 = (int)rintf(f0.x * inv), q1 = (int)rintf(f0.y * inv);
  const int q2 = (int)rintf(f0.z * inv), q3 = (int)rintf(f0.w * inv);
  const int q4 = (int)rintf(f1.x * inv), q5 = (int)rintf(f1.y * inv);
  const int q6 = (int)rintf(f1.z * inv), q7 = (int)rintf(f1.w * inv);
  wq[r * 128 + 2 * l] = (unsigned)(q0 & 255) | ((unsigned)(q1 & 255) << 8) |
                        ((unsigned)(q2 & 255) << 16) | ((unsigned)(q3 & 255) << 24);
  wq[r * 128 + 2 * l + 1] = (unsigned)(q4 & 255) | ((unsigned)(q5 & 255) << 8) |
                            ((unsigned)(q6 & 255) << 16) | ((unsigned)(q7 & 255) << 24);
  if (l == 0) sc[r] = mx * (1.0f / 127.0f);
}

// ---------------------------------------------------------------------------
// xi precompute: xi[bt][r] = x[bt] . W_i2h[r] + b_i2h[r] + b_h2h[r]
// ---------------------------------------------------------------------------
__global__ __launch_bounds__(256) void xi_pre_kernel(
    const float* __restrict__ x, const float* __restrict__ W_i2h,
    const float* __restrict__ b_i2h, const float* __restrict__ b_h2h,
    float* __restrict__ xi) {
  const size_t total = (size_t)B_ * T_ * H_;
  size_t idx = (size_t)blockIdx.x * 256 + threadIdx.x;
  const size_t stride = (size_t)gridDim.x * 256;
  for (; idx < total; idx += stride) {
    const size_t bt = idx >> 9;
    const int r = (int)(idx & (H_ - 1));
    const float* xr = x + bt * I_;
    const float* wr = W_i2h + (size_t)r * I_;
    float s = b_i2h[r] + b_h2h[r];
#pragma unroll
    for (int i = 0; i < I_; ++i) s += wr[i] * xr[i];
    xi[idx] = s;
  }
}

// ---------------------------------------------------------------------------
// Single-CU-per-batch RNN, 1024 threads. Thread (rg=tid>>4, kc=tid&15) owns
// rows [8rg,8rg+8) x k-cols [32kc,32kc+32) of W_h2h as row-scaled i8 in 64
// VGPRs. MODE2: wreg loaded pre-quantized from ws (minimal setup pressure ->
// no AGPR banking); MODE1/0: in-kernel quant fallbacks. sdot4 recurrence on
// two-level i8 h in double-buffered LDS; all-VALU DPP reduce-scatter
// ({15,8,2,1}); 1 barrier/step; zero cross-block traffic.
// r_own = 8rg + 4*kc[2] + 2*kc[3] + kc[1]; (kc,kc^1) pairs duplicate; even
// lane stores.
// ---------------------------------------------------------------------------
template <int MODE>  // 2: wq+xi pre; 1: xi pre only; 0: none
__global__ __launch_bounds__(1024, 4) void rnn_1cu(
    const float* __restrict__ x, const float* __restrict__ noise,
    const float* __restrict__ W_i2h, const float* __restrict__ b_i2h,
    const float* __restrict__ W_h2h, const float* __restrict__ b_h2h,
    const int* __restrict__ taup, const int* __restrict__ dtp,
    const unsigned* __restrict__ wq, const float* __restrict__ sc,
    const float* __restrict__ xi_pre, float* __restrict__ out_rnn) {
  __align__(16) __shared__ char ha_s[2][16 * 48];  // level-1 bytes
  __align__(16) __shared__ char hb_s[2][16 * 48];  // level-2 bytes
  __shared__ float x_s[2][I_];        // MODE0 only
  __shared__ unsigned wi_s[H_ * 12];  // MODE0 only (DCE'd otherwise)

  const int tid = threadIdx.x;
  const int b = blockIdx.x;
  const int rg = tid >> 4;  // 0..63: row group of 8
  const int kc = tid & 15;  // 0..15: k-chunk of 32

  const float alpha = (float)dtp[0] / (float)taup[0];
  const float nzscale = (float)(sqrt(2.0 * (double)alpha) * 0.01);
  const int r_own = 8 * rg + 4 * ((kc >> 2) & 1) + 2 * ((kc >> 3) & 1) +
                    ((kc >> 1) & 1);

  unsigned wreg[64];
  float s_own;
  if (MODE == 2) {
    // ---- load pre-quantized W slice: 16 x dwordx4, no pressure peak ----
    const unsigned* wqt = wq + (size_t)(8 * rg) * 128 + kc * 8;
#pragma unroll
    for (int ro = 0; ro < 8; ++ro) {
      const uint4 a = *(const uint4*)(wqt + (size_t)ro * 128);
      const uint4 c = *(const uint4*)(wqt + (size_t)ro * 128 + 4);
      wreg[ro * 8 + 0] = a.x; wreg[ro * 8 + 1] = a.y;
      wreg[ro * 8 + 2] = a.z; wreg[ro * 8 + 3] = a.w;
      wreg[ro * 8 + 4] = c.x; wreg[ro * 8 + 5] = c.y;
      wreg[ro * 8 + 6] = c.z; wreg[ro * 8 + 7] = c.w;
    }
    s_own = sc[r_own];
  } else {
    // ---- in-kernel two-pass quantization (fallback) ----
    const float* wbase = W_h2h + (size_t)(8 * rg) * H_ + 32 * kc;
    float m[8];
#pragma unroll
    for (int ro = 0; ro < 8; ++ro) {
      float mx = 0.f;
#pragma unroll
      for (int j = 0; j < 8; ++j) {
        const float4 f = *(const float4*)(wbase + (size_t)ro * H_ + 4 * j);
        mx = fmaxf(mx, fmaxf(fmaxf(fabsf(f.x), fabsf(f.y)),
                             fmaxf(fabsf(f.z), fabsf(f.w))));
      }
      m[ro] = mx;
    }
#pragma unroll
    for (int hop = 1; hop <= 8; hop <<= 1)
#pragma unroll
      for (int ro = 0; ro < 8; ++ro)
        m[ro] = fmaxf(m[ro], __shfl_xor(m[ro], hop, 16));
#pragma unroll
    for (int ro = 0; ro < 8; ++ro) {
      const float inv = (m[ro] > 0.f) ? 127.0f / m[ro] : 0.f;
#pragma unroll
      for (int j = 0; j < 8; ++j) {
        const float4 f = *(const float4*)(wbase + (size_t)ro * H_ + 4 * j);
        const int q0 = (int)rintf(f.x * inv), q1 = (int)rintf(f.y * inv);
        const int q2 = (int)rintf(f.z * inv), q3 = (int)rintf(f.w * inv);
        wreg[ro * 8 + j] = (unsigned)(q0 & 255) | ((unsigned)(q1 & 255) << 8) |
                           ((unsigned)(q2 & 255) << 16) |
                           ((unsigned)(q3 & 255) << 24);
      }
    }
    const bool a = (kc >> 2) & 1, bb = (kc >> 3) & 1, c = (kc >> 1) & 1;
    const float mA = c ? m[1] : m[0];
    const float mB = c ? m[3] : m[2];
    const float mC = c ? m[5] : m[4];
    const float mD = c ? m[7] : m[6];
    const float mE = bb ? mB : mA;
    const float mF = bb ? mD : mC;
    s_own = (a ? mF : mE) * (1.0f / 127.0f);
  }

  if (MODE == 0 && tid < H_) {  // W_i2h row as f16 pairs + fused bias
    const float* wr = W_i2h + (size_t)tid * I_;
#pragma unroll
    for (int i2 = 0; i2 < 8; ++i2) {
      const unsigned short lo =
          __builtin_bit_cast(unsigned short, (_Float16)wr[2 * i2]);
      const unsigned short hi =
          __builtin_bit_cast(unsigned short, (_Float16)wr[2 * i2 + 1]);
      wi_s[tid * 12 + i2] = (unsigned)lo | ((unsigned)hi << 16);
    }
    wi_s[tid * 12 + 8] = __float_as_uint(b_i2h[tid] + b_h2h[tid]);
  }
  if (tid < 16 * 48) {  // zero both parities of both h buffers
    ha_s[0][tid] = 0; ha_s[1][tid] = 0;
    hb_s[0][tid] = 0; hb_s[1][tid] = 0;
  }
  if (MODE == 0 && tid < I_) x_s[0][tid] = x[(size_t)b * T_ * I_ + tid];
  if (tid < H_) out_rnn[(size_t)b * (T_ + 1) * H_ + tid] = 0.f;
  __syncthreads();

  const size_t nbase = (size_t)b * T_ * H_;
  const size_t obase = (size_t)b * (T_ + 1) * H_;
  const size_t xbase = (size_t)b * T_ * I_;
  const int wchunk = r_own >> 5, widx = r_own & 31;

  float nzv = noise[nbase + r_own];
  float xiv = (MODE > 0) ? xi_pre[nbase + r_own] : 0.f;

  for (int t = 0; t < T_; ++t) {
    const int p = t & 1;
    // issue NEXT step's loads first (consumed after the barrier)
    const int tn = (t < T_ - 1) ? t + 1 : t;
    const float nz_n = noise[nbase + (size_t)tn * H_ + r_own];
    float xi_n = 0.f;
    if (MODE > 0) xi_n = xi_pre[nbase + (size_t)tn * H_ + r_own];
    if (MODE == 0 && tid < I_)
      x_s[p ^ 1][tid] = x[xbase + (size_t)tn * I_ + tid];

    // h(t) two-level bytes for my k-chunk
    const char* hap = &ha_s[p][kc * 48];
    const char* hbp = &hb_s[p][kc * 48];
    const uint4 A0 = *(const uint4*)hap;
    const uint4 A1 = *(const uint4*)(hap + 16);
    const uint4 B0 = *(const uint4*)hbp;
    const uint4 B1 = *(const uint4*)(hbp + 16);
    float v[8];
#pragma unroll
    for (int ro = 0; ro < 8; ++ro) {
      int a = 0, bb = 0;
      a = sdot4(wreg[ro * 8 + 0], A0.x, a);
      a = sdot4(wreg[ro * 8 + 1], A0.y, a);
      a = sdot4(wreg[ro * 8 + 2], A0.z, a);
      a = sdot4(wreg[ro * 8 + 3], A0.w, a);
      a = sdot4(wreg[ro * 8 + 4], A1.x, a);
      a = sdot4(wreg[ro * 8 + 5], A1.y, a);
      a = sdot4(wreg[ro * 8 + 6], A1.z, a);
      a = sdot4(wreg[ro * 8 + 7], A1.w, a);
      bb = sdot4(wreg[ro * 8 + 0], B0.x, bb);
      bb = sdot4(wreg[ro * 8 + 1], B0.y, bb);
      bb = sdot4(wreg[ro * 8 + 2], B0.z, bb);
      bb = sdot4(wreg[ro * 8 + 3], B0.w, bb);
      bb = sdot4(wreg[ro * 8 + 4], B1.x, bb);
      bb = sdot4(wreg[ro * 8 + 5], B1.y, bb);
      bb = sdot4(wreg[ro * 8 + 6], B1.z, bb);
      bb = sdot4(wreg[ro * 8 + 7], B1.w, bb);
      // exact-to-~1e-7: (a*240+bb) * S2q  (one mad_i32 + cvt + mul)
      v[ro] = (float)(a * 240 + bb) * S2q;
    }
    // ALL-VALU DPP reduce-scatter over the 16 kc lanes
#pragma unroll
    for (int j = 0; j < 4; ++j) {  // L15: partner l^15 (row_mirror)
      const float tl = dppf<DPP_X15>(v[j]);
      const float th = dppf<DPP_X15>(v[j + 4]);
      v[j] = (kc & 4) ? (v[j + 4] + th) : (v[j] + tl);
    }
#pragma unroll
    for (int j = 0; j < 2; ++j) {  // L8: partner l^8 (row_ror:8)
      const float tl = dppf<DPP_X8>(v[j]);
      const float th = dppf<DPP_X8>(v[j + 2]);
      v[j] = (kc & 8) ? (v[j + 2] + th) : (v[j] + tl);
    }
    {  // L2: partner l^2 (quad_perm)
      const float tl = dppf<DPP_X2>(v[0]);
      const float th = dppf<DPP_X2>(v[1]);
      v[0] = (kc & 2) ? (v[1] + th) : (v[0] + tl);
    }
    const float rec = v[0] + dppf<DPP_X1>(v[0]);  // L1 butterfly

    float xfull;
    if (MODE > 0) {
      xfull = xiv;
    } else {
      const uint4 w0 = *(const uint4*)&wi_s[r_own * 12];
      const uint4 w1 = *(const uint4*)&wi_s[r_own * 12 + 4];
      float s = __uint_as_float(wi_s[r_own * 12 + 8]);
      s += f16lo(w0.x) * x_s[p][0] + f16hi(w0.x) * x_s[p][1];
      s += f16lo(w0.y) * x_s[p][2] + f16hi(w0.y) * x_s[p][3];
      s += f16lo(w0.z) * x_s[p][4] + f16hi(w0.z) * x_s[p][5];
      s += f16lo(w0.w) * x_s[p][6] + f16hi(w0.w) * x_s[p][7];
      s += f16lo(w1.x) * x_s[p][8] + f16hi(w1.x) * x_s[p][9];
      s += f16lo(w1.y) * x_s[p][10] + f16hi(w1.y) * x_s[p][11];
      s += f16lo(w1.z) * x_s[p][12] + f16hi(w1.z) * x_s[p][13];
      s += f16lo(w1.w) * x_s[p][14] + f16hi(w1.w) * x_s[p][15];
      xfull = s;
    }
    const float pre = alpha * (xfull + rec * s_own) + nzscale * nzv;
    const float h = fmaxf(pre, 0.f);
    if ((kc & 1) == 0) {
      out_rnn[obase + (size_t)(t + 1) * H_ + r_own] = h;
      int aq = (int)rintf(h * IS1q);
      aq = min(aq, 127);
      const float res = h - (float)aq * S1q;
      const int bq = (int)rintf(res * IS2q);
      ha_s[p ^ 1][wchunk * 48 + widx] = (char)aq;
      hb_s[p ^ 1][wchunk * 48 + widx] = (char)bq;
    }
    __syncthreads();  // h(t+1) staged; buffers flip
    nzv = nz_n;
    xiv = xi_n;
  }
}

// ---------------------------------------------------------------------------
// Post-pass: out_net[b][t] = W_h2o . h_ex(b,t) + b_h2o (t>=1), zeros at t=0.
// ---------------------------------------------------------------------------
__global__ __launch_bounds__(256) void h2o_kernel(
    const float* __restrict__ out_rnn, const float* __restrict__ W_h2o,
    const float* __restrict__ b_h2o, float* __restrict__ out_net) {
  __shared__ float w3[3 * 416];
  const int tid = threadIdx.x;
  for (int idx = tid; idx < O_ * NEX_; idx += 256) {
    const int o = idx / NEX_, e = idx - o * NEX_;
    w3[o * 416 + e] = W_h2o[idx];
  }
  __syncthreads();
  const int wv = tid >> 6, ln = tid & 63;
  const int task = blockIdx.x * 4 + wv;
  if (task >= B_ * (T_ + 1)) return;
  const int bb = task / (T_ + 1), t = task - bb * (T_ + 1);
  float* dst = out_net + (size_t)task * O_;
  if (t == 0) {
    if (ln < O_) dst[ln] = 0.f;
    return;
  }
  const float* hrow = out_rnn + (size_t)task * H_ + NIN_;
  float a0 = 0.f, a1 = 0.f, a2 = 0.f;
  for (int k = ln; k < NEX_; k += 64) {
    const float hv = hrow[k];
    a0 += hv * w3[k];
    a1 += hv * w3[416 + k];
    a2 += hv * w3[832 + k];
  }
#pragma unroll
  for (int off = 32; off >= 1; off >>= 1) {
    a0 += __shfl_xor(a0, off, 64);
    a1 += __shfl_xor(a1, off, 64);
    a2 += __shfl_xor(a2, off, 64);
  }
  if (ln == 0) {
    dst[0] = a0 + b_h2o[0];
    dst[1] = a1 + b_h2o[1];
    dst[2] = a2 + b_h2o[2];
  }
}

extern "C" void kernel_launch(void* const* d_in, const int* in_sizes, int n_in,
                              void* d_out, int out_size, void* d_ws,
                              size_t ws_size, hipStream_t stream) {
  const float* x = (const float*)d_in[0];
  const float* noise = (const float*)d_in[1];
  const float* W_i2h = (const float*)d_in[2];
  const float* b_i2h = (const float*)d_in[3];
  const float* W_h2h = (const float*)d_in[4];
  const float* b_h2h = (const float*)d_in[5];
  const float* W_h2o = (const float*)d_in[6];
  const float* b_h2o = (const float*)d_in[7];
  const int* tau = (const int*)d_in[8];
  const int* dt = (const int*)d_in[9];

  float* out_net = (float*)d_out;
  float* out_rnn = (float*)d_out + (size_t)B_ * (T_ + 1) * O_;

  if (d_ws != nullptr && ws_size >= NEED2) {
    unsigned* wqp = (unsigned*)d_ws;
    float* scp = (float*)((char*)d_ws + WQ_BYTES);
    float* xi = (float*)((char*)d_ws + XI_OFF);
    hipLaunchKernelGGL(quant_w, dim3(H_), dim3(64), 0, stream, W_h2h, wqp, scp);
    hipLaunchKernelGGL(xi_pre_kernel, dim3(2048), dim3(256), 0, stream, x,
                       W_i2h, b_i2h, b_h2h, xi);
    hipLaunchKernelGGL((rnn_1cu<2>), dim3(B_), dim3(1024), 0, stream, x, noise,
                       W_i2h, b_i2h, W_h2h, b_h2h, tau, dt, wqp, scp, xi,
                       out_rnn);
  } else if (d_ws != nullptr && ws_size >= XI_BYTES) {
    float* xi = (float*)d_ws;
    hipLaunchKernelGGL(xi_pre_kernel, dim3(2048), dim3(256), 0, stream, x,
                       W_i2h, b_i2h, b_h2h, xi);
    hipLaunchKernelGGL((rnn_1cu<1>), dim3(B_), dim3(1024), 0, stream, x, noise,
                       W_i2h, b_i2h, W_h2h, b_h2h, tau, dt, (const unsigned*)nullptr,
                       (const float*)nullptr, xi, out_rnn);
  } else {
    hipLaunchKernelGGL((rnn_1cu<0>), dim3(B_), dim3(1024), 0, stream, x, noise,
                       W_i2h, b_i2h, W_h2h, b_h2h, tau, dt, (const unsigned*)nullptr,
                       (const float*)nullptr, (const float*)nullptr, out_rnn);
  }
  hipLaunchKernelGGL(h2o_kernel, dim3((B_ * (T_ + 1) + 3) / 4), dim3(256), 0,
                     stream, out_rnn, W_h2o, b_h2o, out_net);
}